// Round 1
// baseline (428.858 us; speedup 1.0000x reference)
//
#include <hip/hip_runtime.h>
#include <hip/hip_bf16.h>
#include <stdint.h>

typedef _Float16 f16;
typedef __attribute__((ext_vector_type(8))) _Float16 f16x8;
typedef __attribute__((ext_vector_type(4))) float f32x4;

#define NSTEPS 79
#define CDIM   256
#define ROWS   32
#define HSCALE 2048.0f
#define HINV   (1.0f/2048.0f)

// LDS h layout: u32 per (m,k): low16 = f16(h) bits, high16 = f16((h-hi)*2048) bits.
// Byte address = (m*1024 + k*4) ^ ((m&7)<<4)  (XOR swizzle vs stride-1024 conflicts).
__device__ __forceinline__ unsigned hp_off(unsigned m, unsigned kbyte) {
    return ((m << 10) + kbyte) ^ ((m & 7u) << 4);
}

// MFMA layout assumptions (v_mfma_f32_16x16x32_f16):
//   A frag: lane l holds A[m = l&15][k = 8*(l>>4) + i], i=0..7 (consecutive k)
//   B frag: lane l holds B[k = 8*(l>>4) + i][n = l&15]
//   C/D  : lane l, reg r -> C[m = (l>>4)*4 + r][n = l&15]   (verified mapping)

__global__ __launch_bounds__(256, 1) void rnn_fused(
    const float* __restrict__ x0p, const float* __restrict__ x1p,
    const float* __restrict__ x2p, const float* __restrict__ x3p,
    const float* __restrict__ Wx,  const float* __restrict__ Wh,
    const float* __restrict__ brnn,const float* __restrict__ Wd,
    const float* __restrict__ bd,  float* __restrict__ out)
{
    __shared__ __align__(16) float    xs[ROWS][NSTEPS][4];  // 40448 B, time-reversed x
    __shared__ __align__(16) uint32_t hp[2][ROWS][CDIM];    // 65536 B, h hi|lo pairs

    const int tid = (int)threadIdx.x;
    const int wv  = tid >> 6;      // wave 0..3 -> owns N cols [wv*64, wv*64+64)
    const int l   = tid & 63;
    const int q   = l >> 4;
    const int ln  = l & 15;
    const int r0  = (int)blockIdx.x * ROWS;
    const int nc0 = wv * 64;

    // ---------------- Wh -> register fragments (hi and lo*2048) ----------------
    f16x8 B1[4][8], B2[4][8];
    #pragma unroll
    for (int nt = 0; nt < 4; ++nt) {
        const int n = nc0 + nt*16 + ln;
        #pragma unroll
        for (int kt = 0; kt < 8; ++kt) {
            const int kb = kt*32 + q*8;
            f16x8 bh, bl;
            #pragma unroll
            for (int i = 0; i < 8; ++i) {
                float v = Wh[(size_t)(kb + i)*CDIM + n];
                f16 hi = (f16)v;
                f16 lo = (f16)((v - (float)hi) * HSCALE);
                bh[i] = hi; bl[i] = lo;
            }
            B1[nt][kt] = bh;
            B2[nt][kt] = bl;
        }
    }

    // ---- Wx augmented-tile fragments: rows0-3 = Wx_hi / Wx_lo', rows4-31 = 0 ----
    f16x8 B1e[4], B2e[4];
    {
        const f16 z = (f16)0.0f;
        #pragma unroll
        for (int nt = 0; nt < 4; ++nt) {
            const int n = nc0 + nt*16 + ln;
            f16x8 e1 = {z,z,z,z,z,z,z,z};
            f16x8 e2 = {z,z,z,z,z,z,z,z};
            if (q == 0) {
                #pragma unroll
                for (int f = 0; f < 4; ++f) {
                    float v = Wx[f*CDIM + n];
                    f16 hi = (f16)v;
                    f16 lo = (f16)((v - (float)hi) * HSCALE);
                    e1[f] = hi;   // rows 0..3 of aug tile
                    e2[f] = lo;   // rows 0..3 of aug tile (scaled lo)
                }
            }
            B1e[nt] = e1; B2e[nt] = e2;
        }
    }

    float bias_r[4];
    #pragma unroll
    for (int nt = 0; nt < 4; ++nt) bias_r[nt] = brnn[nc0 + nt*16 + ln];

    // ---------------- h0 = 0 ----------------
    for (int idx = tid; idx < ROWS*CDIM; idx += 256) {
        (&hp[0][0][0])[idx] = 0u;
    }
    // ---------------- stage x, reversed in time ----------------
    #pragma unroll
    for (int f = 0; f < 4; ++f) {
        const float* xf = (f==0) ? x0p : (f==1) ? x1p : (f==2) ? x2p : x3p;
        for (int idx = tid; idx < ROWS*NSTEPS; idx += 256) {
            int m  = idx / NSTEPS;
            int lt = idx - m*NSTEPS;
            xs[m][(NSTEPS-1) - lt][f] = xf[(size_t)(r0 + m)*NSTEPS + lt];
        }
    }
    __syncthreads();

    // ---------------- recurrence ----------------
    int p = 0;
    #pragma unroll 1
    for (int t = 0; t < NSTEPS; ++t) {
        const char* rp = (const char*)&hp[p][0][0];
        f32x4 accM[2][4], accC[2][4];
        #pragma unroll
        for (int mt = 0; mt < 2; ++mt)
        #pragma unroll
        for (int nt = 0; nt < 4; ++nt) {
            float b = bias_r[nt];
            f32x4 vb = {b, b, b, b};
            accM[mt][nt] = vb;
            f32x4 vz = {0.f, 0.f, 0.f, 0.f};
            accC[mt][nt] = vz;
        }

        #pragma unroll
        for (int mt = 0; mt < 2; ++mt) {
            const unsigned m = (unsigned)(mt*16 + ln);
            #pragma unroll
            for (int kt = 0; kt < 8; ++kt) {
                const unsigned kb = (unsigned)(kt*32 + q*8) * 4u;
                uint4 u0 = *(const uint4*)(rp + hp_off(m, kb));
                uint4 u1 = *(const uint4*)(rp + hp_off(m, kb + 16u));
                uint4 hw, lw;
                hw.x = (u0.x & 0xFFFFu) | (u0.y << 16);  lw.x = (u0.x >> 16) | (u0.y & 0xFFFF0000u);
                hw.y = (u0.z & 0xFFFFu) | (u0.w << 16);  lw.y = (u0.z >> 16) | (u0.w & 0xFFFF0000u);
                hw.z = (u1.x & 0xFFFFu) | (u1.y << 16);  lw.z = (u1.x >> 16) | (u1.y & 0xFFFF0000u);
                hw.w = (u1.z & 0xFFFFu) | (u1.w << 16);  lw.w = (u1.z >> 16) | (u1.w & 0xFFFF0000u);
                f16x8 a1 = __builtin_bit_cast(f16x8, hw);
                f16x8 a2 = __builtin_bit_cast(f16x8, lw);
                #pragma unroll
                for (int nt = 0; nt < 4; ++nt)
                    accM[mt][nt] = __builtin_amdgcn_mfma_f32_16x16x32_f16(a1, B1[nt][kt], accM[mt][nt], 0, 0, 0);
                #pragma unroll
                for (int nt = 0; nt < 4; ++nt)
                    accC[mt][nt] = __builtin_amdgcn_mfma_f32_16x16x32_f16(a1, B2[nt][kt], accC[mt][nt], 0, 0, 0);
                #pragma unroll
                for (int nt = 0; nt < 4; ++nt)
                    accC[mt][nt] = __builtin_amdgcn_mfma_f32_16x16x32_f16(a2, B1[nt][kt], accC[mt][nt], 0, 0, 0);
            }
            // augmented x-tile: A rows 0-3 = x_hi, 4-7 = x_lo' (q==0 lanes), else 0
            {
                const int mm = mt*16 + ln;
                f32x4 xv = *(const f32x4*)&xs[mm][t][0];
                const f16 z = (f16)0.0f;
                f16x8 a1e = {z,z,z,z,z,z,z,z};
                f16x8 a2e = {z,z,z,z,z,z,z,z};
                if (q == 0) {
                    #pragma unroll
                    for (int f = 0; f < 4; ++f) {
                        float v = xv[f];
                        f16 hi = (f16)v;
                        f16 lo = (f16)((v - (float)hi) * HSCALE);
                        a1e[f]   = hi;
                        a1e[f+4] = lo;
                        a2e[f]   = lo;
                    }
                }
                #pragma unroll
                for (int nt = 0; nt < 4; ++nt)
                    accM[mt][nt] = __builtin_amdgcn_mfma_f32_16x16x32_f16(a1e, B1e[nt], accM[mt][nt], 0, 0, 0);
                #pragma unroll
                for (int nt = 0; nt < 4; ++nt)
                    accC[mt][nt] = __builtin_amdgcn_mfma_f32_16x16x32_f16(a1e, B2e[nt], accC[mt][nt], 0, 0, 0);
                #pragma unroll
                for (int nt = 0; nt < 4; ++nt)
                    accC[mt][nt] = __builtin_amdgcn_mfma_f32_16x16x32_f16(a2e, B1e[nt], accC[mt][nt], 0, 0, 0);
            }
        }

        // epilogue: combine passes, relu, split to hi/lo', pack, write buffer p^1
        {
            char* wp = (char*)&hp[p ^ 1][0][0];
            #pragma unroll
            for (int mt = 0; mt < 2; ++mt)
            #pragma unroll
            for (int nt = 0; nt < 4; ++nt) {
                f32x4 v = accM[mt][nt] + accC[mt][nt] * HINV;
                const unsigned n = (unsigned)(nc0 + nt*16 + ln);
                #pragma unroll
                for (int r = 0; r < 4; ++r) {
                    float hv = v[r];
                    hv = hv > 0.f ? hv : 0.f;
                    const unsigned m = (unsigned)(mt*16 + q*4 + r);
                    f16 hi = (f16)hv;
                    f16 lo = (f16)((hv - (float)hi) * HSCALE);
                    unsigned pk = (unsigned)__builtin_bit_cast(unsigned short, hi)
                                | ((unsigned)__builtin_bit_cast(unsigned short, lo) << 16);
                    *(uint32_t*)(wp + hp_off(m, n * 4u)) = pk;
                }
            }
        }
        __syncthreads();
        p ^= 1;
    }

    // ---------------- final dense layer: out = relu(h @ Wd + b_d) ----------------
    f16x8 D1[4][8], D2[4][8];
    #pragma unroll
    for (int nt = 0; nt < 4; ++nt) {
        const int n = nc0 + nt*16 + ln;
        #pragma unroll
        for (int kt = 0; kt < 8; ++kt) {
            const int kb = kt*32 + q*8;
            f16x8 bh, bl;
            #pragma unroll
            for (int i = 0; i < 8; ++i) {
                float v = Wd[(size_t)(kb + i)*CDIM + n];
                f16 hi = (f16)v;
                f16 lo = (f16)((v - (float)hi) * HSCALE);
                bh[i] = hi; bl[i] = lo;
            }
            D1[nt][kt] = bh;
            D2[nt][kt] = bl;
        }
    }
    {
        const char* rp = (const char*)&hp[p][0][0];
        f32x4 accM[2][4], accC[2][4];
        #pragma unroll
        for (int mt = 0; mt < 2; ++mt)
        #pragma unroll
        for (int nt = 0; nt < 4; ++nt) {
            float b = bd[nc0 + nt*16 + ln];
            f32x4 vb = {b, b, b, b};
            accM[mt][nt] = vb;
            f32x4 vz = {0.f, 0.f, 0.f, 0.f};
            accC[mt][nt] = vz;
        }
        #pragma unroll
        for (int mt = 0; mt < 2; ++mt) {
            const unsigned m = (unsigned)(mt*16 + ln);
            #pragma unroll
            for (int kt = 0; kt < 8; ++kt) {
                const unsigned kb = (unsigned)(kt*32 + q*8) * 4u;
                uint4 u0 = *(const uint4*)(rp + hp_off(m, kb));
                uint4 u1 = *(const uint4*)(rp + hp_off(m, kb + 16u));
                uint4 hw, lw;
                hw.x = (u0.x & 0xFFFFu) | (u0.y << 16);  lw.x = (u0.x >> 16) | (u0.y & 0xFFFF0000u);
                hw.y = (u0.z & 0xFFFFu) | (u0.w << 16);  lw.y = (u0.z >> 16) | (u0.w & 0xFFFF0000u);
                hw.z = (u1.x & 0xFFFFu) | (u1.y << 16);  lw.z = (u1.x >> 16) | (u1.y & 0xFFFF0000u);
                hw.w = (u1.z & 0xFFFFu) | (u1.w << 16);  lw.w = (u1.z >> 16) | (u1.w & 0xFFFF0000u);
                f16x8 a1 = __builtin_bit_cast(f16x8, hw);
                f16x8 a2 = __builtin_bit_cast(f16x8, lw);
                #pragma unroll
                for (int nt = 0; nt < 4; ++nt)
                    accM[mt][nt] = __builtin_amdgcn_mfma_f32_16x16x32_f16(a1, D1[nt][kt], accM[mt][nt], 0, 0, 0);
                #pragma unroll
                for (int nt = 0; nt < 4; ++nt)
                    accC[mt][nt] = __builtin_amdgcn_mfma_f32_16x16x32_f16(a1, D2[nt][kt], accC[mt][nt], 0, 0, 0);
                #pragma unroll
                for (int nt = 0; nt < 4; ++nt)
                    accC[mt][nt] = __builtin_amdgcn_mfma_f32_16x16x32_f16(a2, D1[nt][kt], accC[mt][nt], 0, 0, 0);
            }
        }
        #pragma unroll
        for (int mt = 0; mt < 2; ++mt)
        #pragma unroll
        for (int nt = 0; nt < 4; ++nt) {
            f32x4 v = accM[mt][nt] + accC[mt][nt] * HINV;
            const int n = nc0 + nt*16 + ln;
            #pragma unroll
            for (int r = 0; r < 4; ++r) {
                float ov = v[r] > 0.f ? v[r] : 0.f;
                const int m = mt*16 + q*4 + r;
                out[(size_t)(r0 + m)*CDIM + n] = ov;
            }
        }
    }
}

extern "C" void kernel_launch(void* const* d_in, const int* in_sizes, int n_in,
                              void* d_out, int out_size, void* d_ws, size_t ws_size,
                              hipStream_t stream)
{
    (void)in_sizes; (void)n_in; (void)out_size; (void)d_ws; (void)ws_size;
    const float* x0 = (const float*)d_in[0];
    const float* x1 = (const float*)d_in[1];
    const float* x2 = (const float*)d_in[2];
    const float* x3 = (const float*)d_in[3];
    const float* Wx = (const float*)d_in[4];
    const float* Wh = (const float*)d_in[5];
    const float* br = (const float*)d_in[6];
    const float* Wd = (const float*)d_in[7];
    const float* bd = (const float*)d_in[8];
    float* out = (float*)d_out;

    rnn_fused<<<dim3(8192 / ROWS), dim3(256), 0, stream>>>(
        x0, x1, x2, x3, Wx, Wh, br, Wd, bd, out);
}

// Round 2
// 340.086 us; speedup vs baseline: 1.2610x; 1.2610x over previous
//
#include <hip/hip_runtime.h>
#include <stdint.h>

typedef _Float16 f16;
typedef __attribute__((ext_vector_type(8)))  _Float16 f16x8;
typedef __attribute__((ext_vector_type(16))) float    f32x16;

#define NSTEPS 79
#define CDIM   256
#define ROWS   32
#define HSCALE 2048.0f
#define HINV   (1.0f/2048.0f)

// LDS h layout: u32 per (m,k): low16 = f16(h), high16 = f16((h-hi)*2048).
// Byte address = (m*1024 + k*4) ^ ((m&7)<<4).
__device__ __forceinline__ unsigned hp_off(unsigned m, unsigned kbyte) {
    return ((m << 10) + kbyte) ^ ((m & 7u) << 4);
}

__device__ __forceinline__ uint32_t pack_hl(float v) {
    f16 hi = (f16)v;
    f16 lo = (f16)((v - (float)hi) * HSCALE);
    return (uint32_t)__builtin_bit_cast(unsigned short, hi)
         | ((uint32_t)__builtin_bit_cast(unsigned short, lo) << 16);
}

// MFMA 32x32x16_f16 layout assumptions:
//   A: lane l holds A[m = l&31][k = 8*(l>>5) + i], i=0..7
//   B: lane l holds B[k = 8*(l>>5) + i][n = l&31]
//   C/D: lane l, reg r -> C[row = (r&3) + 8*(r>>2) + 4*(l>>5)][col = l&31]

__global__ __launch_bounds__(512, 2) void rnn_fused(
    const float* __restrict__ x0p, const float* __restrict__ x1p,
    const float* __restrict__ x2p, const float* __restrict__ x3p,
    const float* __restrict__ Wx,  const float* __restrict__ Wh,
    const float* __restrict__ brnn,const float* __restrict__ Wd,
    const float* __restrict__ bd,  float* __restrict__ out)
{
    __shared__ __align__(16) uint32_t xs[ROWS][NSTEPS][4];   // packed hi|lo x, time-reversed
    __shared__ __align__(16) uint32_t hp[2][ROWS][CDIM];     // h hi|lo pairs, swizzled

    const int tid = (int)threadIdx.x;
    const int w   = tid >> 6;          // wave 0..7 -> cols [w*32, w*32+32)
    const int l   = tid & 63;
    const int ln  = l & 31;
    const int h64 = l >> 5;
    const int r0  = (int)blockIdx.x * ROWS;
    const int n   = w * 32 + ln;

    // ---------------- Wh -> register fragments (hi and lo*2048) ----------------
    f16x8 B1[16], B2[16];
    #pragma unroll
    for (int kt = 0; kt < 16; ++kt) {
        const int k0 = kt*16 + h64*8;
        f16x8 bh, bl;
        #pragma unroll
        for (int i = 0; i < 8; ++i) {
            float v = Wh[(size_t)(k0 + i)*CDIM + n];
            f16 hi = (f16)v;
            f16 lo = (f16)((v - (float)hi) * HSCALE);
            bh[i] = hi; bl[i] = lo;
        }
        B1[kt] = bh; B2[kt] = bl;
    }

    // ---- augmented x tiles: accM uses B1e = [Wx_hi(rows0-3); 0]
    //      accC uses B2e = [Wx_lo'(rows0-3); Wx_hi(rows4-7)]
    //      lanes h64==1 (k=8..15) hold zeros -> A-side garbage there is killed.
    f16x8 B1e, B2e;
    {
        const f16 z = (f16)0.0f;
        #pragma unroll
        for (int i = 0; i < 8; ++i) { B1e[i] = z; B2e[i] = z; }
        if (h64 == 0) {
            #pragma unroll
            for (int f = 0; f < 4; ++f) {
                float v = Wx[f*CDIM + n];
                f16 hi = (f16)v;
                f16 lo = (f16)((v - (float)hi) * HSCALE);
                B1e[f]   = hi;
                B2e[f]   = lo;
                B2e[f+4] = hi;
            }
        }
    }

    const float bias  = brnn[n];
    const float biasd = bd[n];

    // ---------------- init h0 = 0; stage x packed+reversed ----------------
    for (int idx = tid; idx < ROWS*CDIM; idx += 512)
        (&hp[0][0][0])[idx] = 0u;
    #pragma unroll
    for (int f = 0; f < 4; ++f) {
        const float* xf = (f==0) ? x0p : (f==1) ? x1p : (f==2) ? x2p : x3p;
        for (int idx = tid; idx < ROWS*NSTEPS; idx += 512) {
            int m  = idx / NSTEPS;
            int lt = idx - m*NSTEPS;
            xs[m][(NSTEPS-1) - lt][f] = pack_hl(xf[(size_t)(r0 + m)*NSTEPS + lt]);
        }
    }
    __syncthreads();

    const unsigned swz   = (unsigned)((ln & 7) << 4);
    const unsigned rbase = (unsigned)(ln << 10) + (unsigned)(h64 * 32);
    char* hp0 = (char*)&hp[0][0][0];
    char* hp1 = (char*)&hp[1][0][0];

    // ---------------- recurrence: 79 steps ----------------
    #pragma unroll 1
    for (int t = 0; t < NSTEPS; ++t) {
        const char* rp = (t & 1) ? hp1 : hp0;
        char*       wp = (t & 1) ? hp0 : hp1;

        f32x16 accM, accC1, accC2;
        #pragma unroll
        for (int r = 0; r < 16; ++r) { accM[r] = bias; accC1[r] = 0.f; accC2[r] = 0.f; }

        // x augmented MFMA (one A tile serves both passes)
        {
            uint4 ux = *(const uint4*)&xs[ln][t][0];
            uint32_t w0 = __builtin_amdgcn_perm(ux.y, ux.x, 0x05040100u); // hi1|hi0
            uint32_t w1 = __builtin_amdgcn_perm(ux.w, ux.z, 0x05040100u); // hi3|hi2
            uint32_t w2 = __builtin_amdgcn_perm(ux.y, ux.x, 0x07060302u); // lo1|lo0
            uint32_t w3 = __builtin_amdgcn_perm(ux.w, ux.z, 0x07060302u); // lo3|lo2
            uint4 au; au.x = w0; au.y = w1; au.z = w2; au.w = w3;
            f16x8 aug = __builtin_bit_cast(f16x8, au);
            accM  = __builtin_amdgcn_mfma_f32_32x32x16_f16(aug, B1e, accM,  0, 0, 0);
            accC1 = __builtin_amdgcn_mfma_f32_32x32x16_f16(aug, B2e, accC1, 0, 0, 0);
        }

        #pragma unroll
        for (int kt = 0; kt < 16; ++kt) {
            const unsigned base = rbase + (unsigned)(kt * 64);
            uint4 u0 = *(const uint4*)(rp + (base ^ swz));
            uint4 u1 = *(const uint4*)(rp + ((base + 16u) ^ swz));
            uint4 hwv, lwv;
            hwv.x = __builtin_amdgcn_perm(u0.y, u0.x, 0x05040100u);
            hwv.y = __builtin_amdgcn_perm(u0.w, u0.z, 0x05040100u);
            hwv.z = __builtin_amdgcn_perm(u1.y, u1.x, 0x05040100u);
            hwv.w = __builtin_amdgcn_perm(u1.w, u1.z, 0x05040100u);
            lwv.x = __builtin_amdgcn_perm(u0.y, u0.x, 0x07060302u);
            lwv.y = __builtin_amdgcn_perm(u0.w, u0.z, 0x07060302u);
            lwv.z = __builtin_amdgcn_perm(u1.y, u1.x, 0x07060302u);
            lwv.w = __builtin_amdgcn_perm(u1.w, u1.z, 0x07060302u);
            f16x8 a1 = __builtin_bit_cast(f16x8, hwv);
            f16x8 a2 = __builtin_bit_cast(f16x8, lwv);
            accM  = __builtin_amdgcn_mfma_f32_32x32x16_f16(a1, B1[kt], accM,  0, 0, 0);
            accC1 = __builtin_amdgcn_mfma_f32_32x32x16_f16(a1, B2[kt], accC1, 0, 0, 0);
            accC2 = __builtin_amdgcn_mfma_f32_32x32x16_f16(a2, B1[kt], accC2, 0, 0, 0);
        }

        // epilogue: combine, relu, split, pack, write other buffer
        #pragma unroll
        for (int r = 0; r < 16; ++r) {
            float v = accM[r] + (accC1[r] + accC2[r]) * HINV;
            v = v > 0.f ? v : 0.f;
            const unsigned mr = (unsigned)((r & 3) + 8*(r >> 2) + 4*h64);
            *(uint32_t*)(wp + hp_off(mr, (unsigned)n * 4u)) = pack_hl(v);
        }
        __syncthreads();
    }

    // ---------------- final dense: out = relu(h @ Wd + b_d) ----------------
    // NSTEPS odd -> final h lives in hp[1]  (t=78 wrote wp=hp1)
    #pragma unroll
    for (int kt = 0; kt < 16; ++kt) {
        const int k0 = kt*16 + h64*8;
        f16x8 bh, bl;
        #pragma unroll
        for (int i = 0; i < 8; ++i) {
            float v = Wd[(size_t)(k0 + i)*CDIM + n];
            f16 hi = (f16)v;
            f16 lo = (f16)((v - (float)hi) * HSCALE);
            bh[i] = hi; bl[i] = lo;
        }
        B1[kt] = bh; B2[kt] = bl;
    }
    {
        const char* rp = hp1;
        f32x16 accM, accC1, accC2;
        #pragma unroll
        for (int r = 0; r < 16; ++r) { accM[r] = biasd; accC1[r] = 0.f; accC2[r] = 0.f; }
        #pragma unroll
        for (int kt = 0; kt < 16; ++kt) {
            const unsigned base = rbase + (unsigned)(kt * 64);
            uint4 u0 = *(const uint4*)(rp + (base ^ swz));
            uint4 u1 = *(const uint4*)(rp + ((base + 16u) ^ swz));
            uint4 hwv, lwv;
            hwv.x = __builtin_amdgcn_perm(u0.y, u0.x, 0x05040100u);
            hwv.y = __builtin_amdgcn_perm(u0.w, u0.z, 0x05040100u);
            hwv.z = __builtin_amdgcn_perm(u1.y, u1.x, 0x05040100u);
            hwv.w = __builtin_amdgcn_perm(u1.w, u1.z, 0x05040100u);
            lwv.x = __builtin_amdgcn_perm(u0.y, u0.x, 0x07060302u);
            lwv.y = __builtin_amdgcn_perm(u0.w, u0.z, 0x07060302u);
            lwv.z = __builtin_amdgcn_perm(u1.y, u1.x, 0x07060302u);
            lwv.w = __builtin_amdgcn_perm(u1.w, u1.z, 0x07060302u);
            f16x8 a1 = __builtin_bit_cast(f16x8, hwv);
            f16x8 a2 = __builtin_bit_cast(f16x8, lwv);
            accM  = __builtin_amdgcn_mfma_f32_32x32x16_f16(a1, B1[kt], accM,  0, 0, 0);
            accC1 = __builtin_amdgcn_mfma_f32_32x32x16_f16(a1, B2[kt], accC1, 0, 0, 0);
            accC2 = __builtin_amdgcn_mfma_f32_32x32x16_f16(a2, B1[kt], accC2, 0, 0, 0);
        }
        #pragma unroll
        for (int r = 0; r < 16; ++r) {
            float v = accM[r] + (accC1[r] + accC2[r]) * HINV;
            v = v > 0.f ? v : 0.f;
            const int mr = (r & 3) + 8*(r >> 2) + 4*h64;
            out[(size_t)(r0 + mr)*CDIM + n] = v;
        }
    }
}

extern "C" void kernel_launch(void* const* d_in, const int* in_sizes, int n_in,
                              void* d_out, int out_size, void* d_ws, size_t ws_size,
                              hipStream_t stream)
{
    (void)in_sizes; (void)n_in; (void)out_size; (void)d_ws; (void)ws_size;
    const float* x0 = (const float*)d_in[0];
    const float* x1 = (const float*)d_in[1];
    const float* x2 = (const float*)d_in[2];
    const float* x3 = (const float*)d_in[3];
    const float* Wx = (const float*)d_in[4];
    const float* Wh = (const float*)d_in[5];
    const float* br = (const float*)d_in[6];
    const float* Wd = (const float*)d_in[7];
    const float* bd = (const float*)d_in[8];
    float* out = (float*)d_out;

    rnn_fused<<<dim3(8192 / ROWS), dim3(512), 0, stream>>>(
        x0, x1, x2, x3, Wx, Wh, br, Wd, bd, out);
}

// Round 3
// 302.868 us; speedup vs baseline: 1.4160x; 1.1229x over previous
//
#include <hip/hip_runtime.h>
#include <stdint.h>

typedef _Float16 f16;
typedef __attribute__((ext_vector_type(8)))  _Float16 f16x8;
typedef __attribute__((ext_vector_type(4)))  float    f32x4;

#define NSTEPS 79
#define CDIM   256
#define ROWS   16
#define NKS    8              // h k-steps (8 x K=32)
#define AUGKS  8              // augmented k-step carrying x
#define PLANE  9216           // bytes per plane: 9 ksteps * 64 chunks * 16B
#define HSCALE 2048.0f
#define HINV   (1.0f/2048.0f)

// ---------------------------------------------------------------------------
// h storage: two f16 planes (hi, lo*2048), FRAGMENT-MAJOR:
//   plane p, kstep ks, chunk dl (0..63), elem i (0..7):
//     holds A[m = dl&15][k = ks*32 + (dl>>4)*8 + i]   (dl = m + 16*kgroup)
//   byte = p*PLANE + ks*1024 + swz(dl,ks)*16 + i*2
//   swz(dl,ks) = dl ^ ((dl>>3)&7) ^ (ks&7)   (bijective; makes both the
//   stride-1 fragment reads AND the column-scatter epilogue writes spread
//   across all 8 bank groups -- verified by hand on (mr=5,n=37),(13,200))
// kstep 8 = augmented x tile: hi=[x_hi(k'0-3), 0], lo=[x_lo'(k'0-3), x_hi(k'4-7)]
//   with B rows [Wx_hi; Wx_lo'] -> accM += x_hi*Wx_hi ;
//   accC += x_lo'*Wx_hi + x_hi*Wx_lo'   (never x_lo'*Wx_lo' -> no 2048^2 blowup)
// ---------------------------------------------------------------------------

__device__ __forceinline__ uint32_t pack_hl(float v) {
    f16 hi = (f16)v;
    f16 lo = (f16)((v - (float)hi) * HSCALE);
    return (uint32_t)__builtin_bit_cast(unsigned short, hi)
         | ((uint32_t)__builtin_bit_cast(unsigned short, lo) << 16);
}

// MFMA 16x16x32_f16 layout (verified in R1):
//   A: lane l holds A[m = l&15][k = 8*(l>>4)+i]
//   B: lane l holds B[k = 8*(l>>4)+i][n = l&15]
//   C/D: lane l, reg r -> C[row = (l>>4)*4 + r][col = l&15]

__global__ __launch_bounds__(512, 4) void rnn_fused(
    const float* __restrict__ x0p, const float* __restrict__ x1p,
    const float* __restrict__ x2p, const float* __restrict__ x3p,
    const float* __restrict__ Wx,  const float* __restrict__ Wh,
    const float* __restrict__ brnn,const float* __restrict__ Wd,
    const float* __restrict__ bd,  float* __restrict__ out)
{
    __shared__ __align__(16) char     hpl[2*PLANE];          // 18432 B
    __shared__ __align__(16) uint32_t xs[ROWS][NSTEPS][4];   // 20224 B, packed hi|lo, reversed

    const int tid  = (int)threadIdx.x;
    const int w    = tid >> 6;        // wave 0..7 -> cols [w*32, w*32+32)
    const int l    = tid & 63;
    const int ln16 = l & 15;
    const int kgl  = l >> 4;          // 0..3
    const int r0   = (int)blockIdx.x * ROWS;
    const int n0   = w * 32;

    char* hb = hpl;

    // -------- Wh-hi fragments + augmented Wx fragment --------
    f16x8 B1[2][NKS];
    f16x8 Baug[2];
    #pragma unroll
    for (int nt = 0; nt < 2; ++nt) {
        const int n = n0 + nt*16 + ln16;
        #pragma unroll
        for (int ks = 0; ks < NKS; ++ks) {
            const int k0 = ks*32 + kgl*8;
            f16x8 b;
            #pragma unroll
            for (int i = 0; i < 8; ++i)
                b[i] = (f16)Wh[(size_t)(k0 + i)*CDIM + n];
            B1[nt][ks] = b;
        }
        f16x8 e;
        #pragma unroll
        for (int i = 0; i < 8; ++i) e[i] = (f16)0.0f;
        if (kgl == 0) {
            #pragma unroll
            for (int i = 0; i < 4; ++i) {
                float wv = Wx[i*CDIM + n];
                e[i]   = (f16)wv;                                   // Wx_hi rows 0-3
                e[i+4] = (f16)((wv - (float)((f16)wv)) * HSCALE);   // Wx_lo' rows 4-7
            }
        }
        Baug[nt] = e;
    }
    const float bias0 = brnn[n0 + ln16];
    const float bias1 = brnn[n0 + 16 + ln16];

    // -------- precomputed LDS addresses --------
    // fragment read base: chunk = l, swz with (ks&7) applied per-kstep
    const unsigned rba = (unsigned)((l ^ ((l >> 3) & 7)) * 16);
    // epilogue write addresses (lane-const): value (mr = kgl*4+r, n = n0+nt*16+ln16)
    //   ksw = n>>5 = w ; kgroup = 2nt + (ln16>>3) ; i = ln16&7 ; dl = mr + 16*kgroup
    int waddr[2][4];
    #pragma unroll
    for (int nt = 0; nt < 2; ++nt) {
        const int kgroup = 2*nt + (ln16 >> 3);
        const int i      = ln16 & 7;
        #pragma unroll
        for (int r = 0; r < 4; ++r) {
            const int mr = kgl*4 + r;
            const int dl = mr + 16*kgroup;
            const int sw = dl ^ ((dl >> 3) & 7) ^ (w & 7);
            waddr[nt][r] = w*1024 + sw*16 + i*2;
        }
    }
    // x-writer (wave 0 lanes): m = ln16, f = kgl
    const int xm    = ln16;
    const int xf4   = kgl;
    const int xswz  = xm ^ ((xm >> 3) & 7);     // ks=8 -> ks&7=0
    const int xaddr = AUGKS*1024 + xswz*16 + xf4*2;
    const int xsbase = xm*NSTEPS*4 + xf4;       // word offset, + t*4 per step

    // -------- init: zero planes, stage x (packed, time-reversed) --------
    for (int i = tid; i < (2*PLANE)/4; i += 512)
        ((uint32_t*)hb)[i] = 0u;
    {
        const float* xfp[4] = {x0p, x1p, x2p, x3p};
        #pragma unroll
        for (int f = 0; f < 4; ++f) {
            const float* xf = xfp[f];
            for (int idx = tid; idx < ROWS*NSTEPS; idx += 512) {
                int m  = idx / NSTEPS;
                int lt = idx - m*NSTEPS;
                xs[m][(NSTEPS-1) - lt][f] = pack_hl(xf[(size_t)(r0 + m)*NSTEPS + lt]);
            }
        }
    }
    __syncthreads();
    // x tile for t=0
    if (tid < 64) {
        uint32_t u = (&xs[0][0][0])[xsbase + 0*4];
        unsigned short hi = (unsigned short)(u & 0xFFFFu);
        unsigned short lo = (unsigned short)(u >> 16);
        *(unsigned short*)(hb + xaddr)             = hi;   // hi-plane k'=f
        *(unsigned short*)(hb + xaddr + PLANE)     = lo;   // lo-plane k'=f
        *(unsigned short*)(hb + xaddr + PLANE + 8) = hi;   // lo-plane k'=4+f
    }
    __syncthreads();

    // -------- recurrence --------
    #pragma unroll 1
    for (int t = 0; t < NSTEPS; ++t) {
        f32x4 accM0 = {bias0, bias0, bias0, bias0};
        f32x4 accM1 = {bias1, bias1, bias1, bias1};
        f32x4 accC0 = {0.f, 0.f, 0.f, 0.f};
        f32x4 accC1 = {0.f, 0.f, 0.f, 0.f};

        #pragma unroll
        for (int ks = 0; ks < NKS; ++ks) {
            const unsigned ra = (unsigned)(ks*1024) + (rba ^ (unsigned)((ks & 7) << 4));
            f16x8 a1 = *(const f16x8*)(hb + ra);
            f16x8 a2 = *(const f16x8*)(hb + PLANE + ra);
            accM0 = __builtin_amdgcn_mfma_f32_16x16x32_f16(a1, B1[0][ks], accM0, 0, 0, 0);
            accM1 = __builtin_amdgcn_mfma_f32_16x16x32_f16(a1, B1[1][ks], accM1, 0, 0, 0);
            accC0 = __builtin_amdgcn_mfma_f32_16x16x32_f16(a2, B1[0][ks], accC0, 0, 0, 0);
            accC1 = __builtin_amdgcn_mfma_f32_16x16x32_f16(a2, B1[1][ks], accC1, 0, 0, 0);
        }
        {   // augmented x k-step
            const unsigned ra = (unsigned)(AUGKS*1024) + rba;
            f16x8 a1 = *(const f16x8*)(hb + ra);
            f16x8 a2 = *(const f16x8*)(hb + PLANE + ra);
            accM0 = __builtin_amdgcn_mfma_f32_16x16x32_f16(a1, Baug[0], accM0, 0, 0, 0);
            accM1 = __builtin_amdgcn_mfma_f32_16x16x32_f16(a1, Baug[1], accM1, 0, 0, 0);
            accC0 = __builtin_amdgcn_mfma_f32_16x16x32_f16(a2, Baug[0], accC0, 0, 0, 0);
            accC1 = __builtin_amdgcn_mfma_f32_16x16x32_f16(a2, Baug[1], accC1, 0, 0, 0);
        }

        __syncthreads();   // all fragment reads complete before overwriting h

        // next step's x tile
        if (tid < 64 && t + 1 < NSTEPS) {
            uint32_t u = (&xs[0][0][0])[xsbase + (t+1)*4];
            unsigned short hi = (unsigned short)(u & 0xFFFFu);
            unsigned short lo = (unsigned short)(u >> 16);
            *(unsigned short*)(hb + xaddr)             = hi;
            *(unsigned short*)(hb + xaddr + PLANE)     = lo;
            *(unsigned short*)(hb + xaddr + PLANE + 8) = hi;
        }
        // h writes: combine planes, relu, split
        #pragma unroll
        for (int r = 0; r < 4; ++r) {
            float v0 = accM0[r] + accC0[r]*HINV;
            v0 = v0 > 0.f ? v0 : 0.f;
            f16 h0 = (f16)v0;
            f16 l0 = (f16)((v0 - (float)h0)*HSCALE);
            *(f16*)(hb + waddr[0][r])         = h0;
            *(f16*)(hb + waddr[0][r] + PLANE) = l0;
            float v1 = accM1[r] + accC1[r]*HINV;
            v1 = v1 > 0.f ? v1 : 0.f;
            f16 h1 = (f16)v1;
            f16 l1 = (f16)((v1 - (float)h1)*HSCALE);
            *(f16*)(hb + waddr[1][r])         = h1;
            *(f16*)(hb + waddr[1][r] + PLANE) = l1;
        }
        __syncthreads();   // new h visible
    }

    // -------- final dense: out = relu(h @ Wd + b_d) --------
    f16x8 D1[2][NKS];
    #pragma unroll
    for (int nt = 0; nt < 2; ++nt) {
        const int n = n0 + nt*16 + ln16;
        #pragma unroll
        for (int ks = 0; ks < NKS; ++ks) {
            const int k0 = ks*32 + kgl*8;
            f16x8 b;
            #pragma unroll
            for (int i = 0; i < 8; ++i)
                b[i] = (f16)Wd[(size_t)(k0 + i)*CDIM + n];
            D1[nt][ks] = b;
        }
    }
    {
        const float bd0 = bd[n0 + ln16];
        const float bd1 = bd[n0 + 16 + ln16];
        f32x4 accM0 = {bd0, bd0, bd0, bd0};
        f32x4 accM1 = {bd1, bd1, bd1, bd1};
        f32x4 accC0 = {0.f, 0.f, 0.f, 0.f};
        f32x4 accC1 = {0.f, 0.f, 0.f, 0.f};
        #pragma unroll
        for (int ks = 0; ks < NKS; ++ks) {
            const unsigned ra = (unsigned)(ks*1024) + (rba ^ (unsigned)((ks & 7) << 4));
            f16x8 a1 = *(const f16x8*)(hb + ra);
            f16x8 a2 = *(const f16x8*)(hb + PLANE + ra);
            accM0 = __builtin_amdgcn_mfma_f32_16x16x32_f16(a1, D1[0][ks], accM0, 0, 0, 0);
            accM1 = __builtin_amdgcn_mfma_f32_16x16x32_f16(a1, D1[1][ks], accM1, 0, 0, 0);
            accC0 = __builtin_amdgcn_mfma_f32_16x16x32_f16(a2, D1[0][ks], accC0, 0, 0, 0);
            accC1 = __builtin_amdgcn_mfma_f32_16x16x32_f16(a2, D1[1][ks], accC1, 0, 0, 0);
        }
        #pragma unroll
        for (int r = 0; r < 4; ++r) {
            const int mr = kgl*4 + r;
            float v0 = accM0[r] + accC0[r]*HINV;
            v0 = v0 > 0.f ? v0 : 0.f;
            out[(size_t)(r0 + mr)*CDIM + (n0 + ln16)] = v0;
            float v1 = accM1[r] + accC1[r]*HINV;
            v1 = v1 > 0.f ? v1 : 0.f;
            out[(size_t)(r0 + mr)*CDIM + (n0 + 16 + ln16)] = v1;
        }
    }
}

extern "C" void kernel_launch(void* const* d_in, const int* in_sizes, int n_in,
                              void* d_out, int out_size, void* d_ws, size_t ws_size,
                              hipStream_t stream)
{
    (void)in_sizes; (void)n_in; (void)out_size; (void)d_ws; (void)ws_size;
    const float* x0 = (const float*)d_in[0];
    const float* x1 = (const float*)d_in[1];
    const float* x2 = (const float*)d_in[2];
    const float* x3 = (const float*)d_in[3];
    const float* Wx = (const float*)d_in[4];
    const float* Wh = (const float*)d_in[5];
    const float* br = (const float*)d_in[6];
    const float* Wd = (const float*)d_in[7];
    const float* bd = (const float*)d_in[8];
    float* out = (float*)d_out;

    rnn_fused<<<dim3(8192 / ROWS), dim3(512), 0, stream>>>(
        x0, x1, x2, x3, Wx, Wh, br, Wd, bd, out);
}

// Round 4
// 301.615 us; speedup vs baseline: 1.4219x; 1.0042x over previous
//
#include <hip/hip_runtime.h>
#include <stdint.h>

typedef _Float16 f16;
typedef __attribute__((ext_vector_type(8)))  _Float16 f16x8;
typedef __attribute__((ext_vector_type(4)))  float    f32x4;

#define NSTEPS 79
#define CDIM   256
#define ROWS   16
#define NKS    8              // h k-steps (8 x K=32)
#define AUGKS  8              // augmented k-step carrying x
#define PLANE  9216           // bytes per plane: 9 ksteps * 64 chunks * 16B

// ---------------------------------------------------------------------------
// h storage: two f16 planes, FRAGMENT-MAJOR:
//   hi-plane: f16(h);  lo-plane: f16(h - hi)   (UNSCALED -> same B operand,
//   single accumulator: acc += a_hi*B + a_lo*B)
//   plane p, kstep ks, chunk dl (0..63), elem i (0..7):
//     holds A[m = dl&15][k = ks*32 + (dl>>4)*8 + i]
//   byte = p*PLANE + ks*1024 + swz(dl,ks)*16 + i*2,  swz = dl ^ ((dl>>3)&7) ^ (ks&7)
// kstep 8 = augmented x tile:
//   hi-plane: [x_hi (k'0-3), x_lo (k'4-7)]  x  Baug1 = [Wx_hi; Wx_hi]
//   lo-plane: [x_hi (k'0-3), 0   (k'4-7)]  x  Baug2 = [Wx_lo; 0]
//   => x_hi*Wx_hi + x_lo*Wx_hi + x_hi*Wx_lo  (x_lo*Wx_lo dropped, negligible)
// Wh/Wd lo-planes dropped (validated R3: absmax 0.0156 << 0.066 threshold).
// ---------------------------------------------------------------------------

__device__ __forceinline__ uint32_t pack_hl(float v) {
    f16 hi = (f16)v;
    f16 lo = (f16)(v - (float)hi);
    return (uint32_t)__builtin_bit_cast(unsigned short, hi)
         | ((uint32_t)__builtin_bit_cast(unsigned short, lo) << 16);
}

// MFMA 16x16x32_f16 layout (verified R1):
//   A: lane l holds A[m = l&15][k = 8*(l>>4)+i]
//   B: lane l holds B[k = 8*(l>>4)+i][n = l&15]
//   C/D: lane l, reg r -> C[row = (l>>4)*4 + r][col = l&15]

__global__ __launch_bounds__(512, 4) void rnn_fused(
    const float* __restrict__ x0p, const float* __restrict__ x1p,
    const float* __restrict__ x2p, const float* __restrict__ x3p,
    const float* __restrict__ Wx,  const float* __restrict__ Wh,
    const float* __restrict__ brnn,const float* __restrict__ Wd,
    const float* __restrict__ bd,  float* __restrict__ out)
{
    __shared__ __align__(16) char     hpl[2*PLANE];          // 18432 B
    __shared__ __align__(16) uint32_t xs[ROWS][NSTEPS][4];   // 20224 B, packed hi|lo, reversed

    const int tid  = (int)threadIdx.x;
    const int w    = tid >> 6;        // wave 0..7 -> cols [w*32, w*32+32)
    const int l    = tid & 63;
    const int ln16 = l & 15;
    const int kgl  = l >> 4;          // 0..3
    const int r0   = (int)blockIdx.x * ROWS;
    const int n0   = w * 32;

    char* hb = hpl;

    // -------- Wh-hi fragments + augmented Wx fragments --------
    f16x8 B1[2][NKS];          // reused for Wd after the recurrence
    f16x8 Baug1[2], Baug2[2];
    #pragma unroll
    for (int nt = 0; nt < 2; ++nt) {
        const int n = n0 + nt*16 + ln16;
        #pragma unroll
        for (int ks = 0; ks < NKS; ++ks) {
            const int k0 = ks*32 + kgl*8;
            f16x8 b;
            #pragma unroll
            for (int i = 0; i < 8; ++i)
                b[i] = (f16)Wh[(size_t)(k0 + i)*CDIM + n];
            B1[nt][ks] = b;
        }
        f16x8 e1, e2;
        #pragma unroll
        for (int i = 0; i < 8; ++i) { e1[i] = (f16)0.0f; e2[i] = (f16)0.0f; }
        if (kgl == 0) {
            #pragma unroll
            for (int i = 0; i < 4; ++i) {
                float wv = Wx[i*CDIM + n];
                f16 whi = (f16)wv;
                e1[i]   = whi;                       // rows 0-3: Wx_hi
                e1[i+4] = whi;                       // rows 4-7: Wx_hi (vs x_lo)
                e2[i]   = (f16)(wv - (float)whi);    // rows 0-3: Wx_lo (vs x_hi)
            }
        }
        Baug1[nt] = e1; Baug2[nt] = e2;
    }
    const float bias0 = brnn[n0 + ln16];
    const float bias1 = brnn[n0 + 16 + ln16];

    // -------- precomputed LDS addresses --------
    const unsigned rba = (unsigned)((l ^ ((l >> 3) & 7)) * 16);
    int waddr[2][4];
    #pragma unroll
    for (int nt = 0; nt < 2; ++nt) {
        const int kgroup = 2*nt + (ln16 >> 3);
        const int i      = ln16 & 7;
        #pragma unroll
        for (int r = 0; r < 4; ++r) {
            const int mr = kgl*4 + r;
            const int dl = mr + 16*kgroup;
            const int sw = dl ^ ((dl >> 3) & 7) ^ (w & 7);
            waddr[nt][r] = w*1024 + sw*16 + i*2;
        }
    }
    // x-writer (wave 0 lanes): m = ln16, f = kgl
    const int xm    = ln16;
    const int xf4   = kgl;
    const int xswz  = xm ^ ((xm >> 3) & 7);     // ks=8 -> ks&7=0
    const int xaddr = AUGKS*1024 + xswz*16 + xf4*2;
    const int xsbase = xm*NSTEPS*4 + xf4;       // word offset, + t*4 per step

    // -------- init: zero planes, stage x (packed, time-reversed) --------
    for (int i = tid; i < (2*PLANE)/4; i += 512)
        ((uint32_t*)hb)[i] = 0u;
    {
        const float* xfp[4] = {x0p, x1p, x2p, x3p};
        #pragma unroll
        for (int f = 0; f < 4; ++f) {
            const float* xf = xfp[f];
            for (int idx = tid; idx < ROWS*NSTEPS; idx += 512) {
                int m  = idx / NSTEPS;
                int lt = idx - m*NSTEPS;
                xs[m][(NSTEPS-1) - lt][f] = pack_hl(xf[(size_t)(r0 + m)*NSTEPS + lt]);
            }
        }
    }
    __syncthreads();
    // x tile for t=0
    if (tid < 64) {
        uint32_t u = (&xs[0][0][0])[xsbase + 0*4];
        unsigned short hi = (unsigned short)(u & 0xFFFFu);
        unsigned short lo = (unsigned short)(u >> 16);
        *(unsigned short*)(hb + xaddr)         = hi;   // hi-plane k'=f   (x_hi)
        *(unsigned short*)(hb + xaddr + 8)     = lo;   // hi-plane k'=4+f (x_lo)
        *(unsigned short*)(hb + xaddr + PLANE) = hi;   // lo-plane k'=f   (x_hi)
    }
    __syncthreads();

    // -------- recurrence --------
    #pragma unroll 1
    for (int t = 0; t < NSTEPS; ++t) {
        f32x4 acc0 = {bias0, bias0, bias0, bias0};
        f32x4 acc1 = {bias1, bias1, bias1, bias1};

        #pragma unroll
        for (int ks = 0; ks < NKS; ++ks) {
            const unsigned ra = (unsigned)(ks*1024) + (rba ^ (unsigned)((ks & 7) << 4));
            f16x8 a1 = *(const f16x8*)(hb + ra);
            f16x8 a2 = *(const f16x8*)(hb + PLANE + ra);
            acc0 = __builtin_amdgcn_mfma_f32_16x16x32_f16(a1, B1[0][ks], acc0, 0, 0, 0);
            acc1 = __builtin_amdgcn_mfma_f32_16x16x32_f16(a1, B1[1][ks], acc1, 0, 0, 0);
            acc0 = __builtin_amdgcn_mfma_f32_16x16x32_f16(a2, B1[0][ks], acc0, 0, 0, 0);
            acc1 = __builtin_amdgcn_mfma_f32_16x16x32_f16(a2, B1[1][ks], acc1, 0, 0, 0);
        }
        {   // augmented x k-step
            const unsigned ra = (unsigned)(AUGKS*1024) + rba;
            f16x8 a1 = *(const f16x8*)(hb + ra);
            f16x8 a2 = *(const f16x8*)(hb + PLANE + ra);
            acc0 = __builtin_amdgcn_mfma_f32_16x16x32_f16(a1, Baug1[0], acc0, 0, 0, 0);
            acc1 = __builtin_amdgcn_mfma_f32_16x16x32_f16(a1, Baug1[1], acc1, 0, 0, 0);
            acc0 = __builtin_amdgcn_mfma_f32_16x16x32_f16(a2, Baug2[0], acc0, 0, 0, 0);
            acc1 = __builtin_amdgcn_mfma_f32_16x16x32_f16(a2, Baug2[1], acc1, 0, 0, 0);
        }

        __syncthreads();   // all fragment reads complete before overwriting h

        // next step's x tile
        if (tid < 64 && t + 1 < NSTEPS) {
            uint32_t u = (&xs[0][0][0])[xsbase + (t+1)*4];
            unsigned short hi = (unsigned short)(u & 0xFFFFu);
            unsigned short lo = (unsigned short)(u >> 16);
            *(unsigned short*)(hb + xaddr)         = hi;
            *(unsigned short*)(hb + xaddr + 8)     = lo;
            *(unsigned short*)(hb + xaddr + PLANE) = hi;
        }
        // h writes: relu, split hi/lo (unscaled), store both planes
        #pragma unroll
        for (int r = 0; r < 4; ++r) {
            float v0 = acc0[r];
            v0 = v0 > 0.f ? v0 : 0.f;
            f16 h0 = (f16)v0;
            f16 l0 = (f16)(v0 - (float)h0);
            *(f16*)(hb + waddr[0][r])         = h0;
            *(f16*)(hb + waddr[0][r] + PLANE) = l0;
            float v1 = acc1[r];
            v1 = v1 > 0.f ? v1 : 0.f;
            f16 h1 = (f16)v1;
            f16 l1 = (f16)(v1 - (float)h1);
            *(f16*)(hb + waddr[1][r])         = h1;
            *(f16*)(hb + waddr[1][r] + PLANE) = l1;
        }
        __syncthreads();   // new h visible
    }

    // -------- final dense: out = relu(h @ Wd + b_d), reuse B1 regs --------
    #pragma unroll
    for (int nt = 0; nt < 2; ++nt) {
        const int n = n0 + nt*16 + ln16;
        #pragma unroll
        for (int ks = 0; ks < NKS; ++ks) {
            const int k0 = ks*32 + kgl*8;
            f16x8 b;
            #pragma unroll
            for (int i = 0; i < 8; ++i)
                b[i] = (f16)Wd[(size_t)(k0 + i)*CDIM + n];
            B1[nt][ks] = b;
        }
    }
    {
        const float bd0 = bd[n0 + ln16];
        const float bd1 = bd[n0 + 16 + ln16];
        f32x4 acc0 = {bd0, bd0, bd0, bd0};
        f32x4 acc1 = {bd1, bd1, bd1, bd1};
        #pragma unroll
        for (int ks = 0; ks < NKS; ++ks) {
            const unsigned ra = (unsigned)(ks*1024) + (rba ^ (unsigned)((ks & 7) << 4));
            f16x8 a1 = *(const f16x8*)(hb + ra);
            f16x8 a2 = *(const f16x8*)(hb + PLANE + ra);
            acc0 = __builtin_amdgcn_mfma_f32_16x16x32_f16(a1, B1[0][ks], acc0, 0, 0, 0);
            acc1 = __builtin_amdgcn_mfma_f32_16x16x32_f16(a1, B1[1][ks], acc1, 0, 0, 0);
            acc0 = __builtin_amdgcn_mfma_f32_16x16x32_f16(a2, B1[0][ks], acc0, 0, 0, 0);
            acc1 = __builtin_amdgcn_mfma_f32_16x16x32_f16(a2, B1[1][ks], acc1, 0, 0, 0);
        }
        #pragma unroll
        for (int r = 0; r < 4; ++r) {
            const int mr = kgl*4 + r;
            float v0 = acc0[r];
            v0 = v0 > 0.f ? v0 : 0.f;
            out[(size_t)(r0 + mr)*CDIM + (n0 + ln16)] = v0;
            float v1 = acc1[r];
            v1 = v1 > 0.f ? v1 : 0.f;
            out[(size_t)(r0 + mr)*CDIM + (n0 + 16 + ln16)] = v1;
        }
    }
}

extern "C" void kernel_launch(void* const* d_in, const int* in_sizes, int n_in,
                              void* d_out, int out_size, void* d_ws, size_t ws_size,
                              hipStream_t stream)
{
    (void)in_sizes; (void)n_in; (void)out_size; (void)d_ws; (void)ws_size;
    const float* x0 = (const float*)d_in[0];
    const float* x1 = (const float*)d_in[1];
    const float* x2 = (const float*)d_in[2];
    const float* x3 = (const float*)d_in[3];
    const float* Wx = (const float*)d_in[4];
    const float* Wh = (const float*)d_in[5];
    const float* br = (const float*)d_in[6];
    const float* Wd = (const float*)d_in[7];
    const float* bd = (const float*)d_in[8];
    float* out = (float*)d_out;

    rnn_fused<<<dim3(8192 / ROWS), dim3(512), 0, stream>>>(
        x0, x1, x2, x3, Wx, Wh, br, Wd, bd, out);
}